// Round 1
// baseline (386.934 us; speedup 1.0000x reference)
//
#include <hip/hip_runtime.h>
#include <math.h>

// S4 conv: y = irfft(rfft(u,8192)*rfft(K,8192), 8192)[:4096] + D*u
// K shared across all 16*512 = 8192 rows.
//
// Pipeline (all per-launch, deterministic):
//  k_prep    (fp64): B = Vc@Bp, products conj(Ct)*B etc., step = exp(log_step)
//  k_atroots (fp64): generating function at 4096 roots of unity -> at_roots (stored fp32)
//  k_kt      (fp32): K[t] = Re(ifft_4096(at_roots))      (direct DFT, wave per t)
//  k_kf      (fp32): Kf[k] = fft_8192([K,0])/8192, stored bit-reversed (wave per k)
//  k_conv    (fp32): 2 rows packed as complex; radix-2 DIF fwd -> pointwise -> DIT inv in LDS

#define SEQ_L 4096
#define NFFT  8192
#define NST   64
#define NROWS 8192

__device__ __forceinline__ double2 dcmul(double2 a, double2 b) {
  return make_double2(a.x*b.x - a.y*b.y, a.x*b.y + a.y*b.x);
}

// ---------------------------------------------------------------- k_prep
__global__ __launch_bounds__(64) void k_prep(
    const float* __restrict__ Lam_ri, const float* __restrict__ p_ri,
    const float* __restrict__ q_ri,  const float* __restrict__ Vc_ri,
    const float* __restrict__ Ct_ri, const float* __restrict__ Bp,
    const float* __restrict__ log_step,
    double2* __restrict__ lam, double2* __restrict__ ctB,
    double2* __restrict__ ctp, double2* __restrict__ qB,
    double2* __restrict__ qp,  double* __restrict__ stepp) {
  int n = threadIdx.x;
  if (n >= NST) return;
  double lr = Lam_ri[2*n], li = Lam_ri[2*n+1];
  double pr = p_ri[2*n],  pi = p_ri[2*n+1];
  double qr = q_ri[2*n],  qi = q_ri[2*n+1];
  double cr = Ct_ri[2*n], ci = Ct_ri[2*n+1];
  double br = 0.0, bi = 0.0;
  for (int m = 0; m < NST; ++m) {
    double b = (double)Bp[m];
    br += (double)Vc_ri[2*(n*NST+m)]   * b;
    bi += (double)Vc_ri[2*(n*NST+m)+1] * b;
  }
  lam[n] = make_double2(lr, li);
  // conj(Ct)*B, conj(Ct)*p, conj(q)*B, conj(q)*p
  ctB[n] = make_double2(cr*br + ci*bi, cr*bi - ci*br);
  ctp[n] = make_double2(cr*pr + ci*pi, cr*pi - ci*pr);
  qB[n]  = make_double2(qr*br + qi*bi, qr*bi - qi*br);
  qp[n]  = make_double2(qr*pr + qi*pi, qr*pi - qi*pr);
  if (n == 0) *stepp = exp((double)log_step[0]);
}

// ---------------------------------------------------------------- k_atroots
__global__ __launch_bounds__(256) void k_atroots(
    const double2* __restrict__ lam, const double2* __restrict__ ctB,
    const double2* __restrict__ ctp, const double2* __restrict__ qB,
    const double2* __restrict__ qp,  const double* __restrict__ stepp,
    float2* __restrict__ atroots) {
  int l = blockIdx.x * blockDim.x + threadIdx.x;
  if (l >= SEQ_L) return;
  double step = *stepp;
  double ang = -2.0 * M_PI * (double)l / (double)SEQ_L;
  double sn, cs;
  sincos(ang, &sn, &cs);
  double2 onem = make_double2(1.0 - cs, -sn);
  double2 onep = make_double2(1.0 + cs,  sn);
  double den = onep.x*onep.x + onep.y*onep.y;
  double2 ip = make_double2(onep.x/den, -onep.y/den);   // 1/(1+Omega)
  double2 g  = dcmul(onem, ip);
  double tw = 2.0 / step;
  g.x *= tw; g.y *= tw;                                  // (2/step)(1-O)/(1+O)
  double2 cc = make_double2(2.0*ip.x, 2.0*ip.y);         // 2/(1+O)
  double2 k00 = make_double2(0,0), k01 = make_double2(0,0);
  double2 k10 = make_double2(0,0), k11 = make_double2(0,0);
  for (int n = 0; n < NST; ++n) {
    double2 L = lam[n];
    double2 d = make_double2(g.x - L.x, g.y - L.y);
    double dd = d.x*d.x + d.y*d.y;
    double2 inv = make_double2(d.x/dd, -d.y/dd);
    double2 v;
    v = ctB[n]; k00.x += v.x*inv.x - v.y*inv.y; k00.y += v.x*inv.y + v.y*inv.x;
    v = ctp[n]; k01.x += v.x*inv.x - v.y*inv.y; k01.y += v.x*inv.y + v.y*inv.x;
    v = qB[n];  k10.x += v.x*inv.x - v.y*inv.y; k10.y += v.x*inv.y + v.y*inv.x;
    v = qp[n];  k11.x += v.x*inv.x - v.y*inv.y; k11.y += v.x*inv.y + v.y*inv.x;
  }
  double2 k11p = make_double2(1.0 + k11.x, k11.y);
  double2 num  = dcmul(k01, k10);
  double dd2 = k11p.x*k11p.x + k11p.y*k11p.y;
  double2 t = make_double2((num.x*k11p.x + num.y*k11p.y)/dd2,
                           (num.y*k11p.x - num.x*k11p.y)/dd2);
  double2 inner = make_double2(k00.x - t.x, k00.y - t.y);
  double2 at = dcmul(cc, inner);
  atroots[l] = make_float2((float)at.x, (float)at.y);
}

// ---------------------------------------------------------------- k_kt
// K[t] = Re( (1/4096) * sum_l at_roots[l] * exp(+2*pi*i*l*t/4096) ), one wave per t
__global__ __launch_bounds__(512) void k_kt(const float2* __restrict__ atroots,
                                            float* __restrict__ Kt) {
  int gid  = blockIdx.x * 512 + threadIdx.x;
  int t    = gid >> 6;
  int lane = gid & 63;
  float acc = 0.f;
  for (int l = lane; l < SEQ_L; l += 64) {
    int ph = (l * t) & (SEQ_L - 1);
    float a = (float)ph * (6.28318530717958647692f / (float)SEQ_L);
    float sn, cs; __sincosf(a, &sn, &cs);
    float2 v = atroots[l];
    acc += v.x*cs - v.y*sn;
  }
  for (int off = 32; off > 0; off >>= 1) acc += __shfl_down(acc, off, 64);
  if (lane == 0) Kt[t] = acc * (1.0f / (float)SEQ_L);
}

// ---------------------------------------------------------------- k_kf
// Kf[k] = (1/8192) * sum_t K[t] * exp(-2*pi*i*k*t/8192), stored at bitrev13(k)
__global__ __launch_bounds__(512) void k_kf(const float* __restrict__ Kt,
                                            float2* __restrict__ kf_br) {
  int gid  = blockIdx.x * 512 + threadIdx.x;
  int k    = gid >> 6;
  int lane = gid & 63;
  float ar = 0.f, ai = 0.f;
  for (int t = lane; t < SEQ_L; t += 64) {
    int ph = (k * t) & (NFFT - 1);
    float a = (float)ph * (-6.28318530717958647692f / (float)NFFT);
    float sn, cs; __sincosf(a, &sn, &cs);
    float kv = Kt[t];
    ar += kv * cs; ai += kv * sn;
  }
  for (int off = 32; off > 0; off >>= 1) {
    ar += __shfl_down(ar, off, 64);
    ai += __shfl_down(ai, off, 64);
  }
  if (lane == 0) {
    unsigned r = __brev((unsigned)k) >> 19;   // 13-bit reversal
    kf_br[r] = make_float2(ar * (1.0f/(float)NFFT), ai * (1.0f/(float)NFFT));
  }
}

// ---------------------------------------------------------------- k_conv
// Two real rows packed as one complex sequence. DIF fwd (natural->bitrev),
// pointwise multiply with bit-reversed Kf (includes 1/N), DIT inv (bitrev->natural).
__global__ __launch_bounds__(512) void k_conv(const float* __restrict__ u,
                                              const float2* __restrict__ kf_br,
                                              const float* __restrict__ Dp,
                                              float* __restrict__ out) {
  __shared__ float2 z[NFFT];
  int tid = threadIdx.x;
  size_t row0 = (size_t)blockIdx.x * 2;
  const float* u0 = u + row0 * SEQ_L;
  const float* u1 = u0 + SEQ_L;

  #pragma unroll
  for (int i = 0; i < 8; ++i) {
    int t = tid + i * 512;
    z[t]         = make_float2(u0[t], u1[t]);
    z[t + SEQ_L] = make_float2(0.f, 0.f);
  }
  __syncthreads();

  // forward DIF radix-2: 13 stages
  for (int m = NFFT; m >= 2; m >>= 1) {
    int half = m >> 1;
    float wstep = -6.28318530717958647692f / (float)m;
    #pragma unroll
    for (int i = 0; i < 8; ++i) {
      int idx = tid + i * 512;          // 0..4095
      int j   = idx & (half - 1);
      int i0  = 2 * idx - j;
      int i1  = i0 + half;
      float2 a = z[i0];
      float2 b = z[i1];
      float2 s = make_float2(a.x + b.x, a.y + b.y);
      float2 d = make_float2(a.x - b.x, a.y - b.y);
      float sn, cs; __sincosf(wstep * (float)j, &sn, &cs);
      z[i0] = s;
      z[i1] = make_float2(d.x*cs - d.y*sn, d.x*sn + d.y*cs);
    }
    __syncthreads();
  }

  // pointwise: z *= Kf (bit-reversed order on both sides)
  #pragma unroll
  for (int i = 0; i < 16; ++i) {
    int t = tid + i * 512;
    float2 a = z[t], k = kf_br[t];
    z[t] = make_float2(a.x*k.x - a.y*k.y, a.x*k.y + a.y*k.x);
  }
  __syncthreads();

  // inverse DIT radix-2: 13 stages (conjugate twiddles; 1/N folded into Kf)
  for (int m = 2; m <= NFFT; m <<= 1) {
    int half = m >> 1;
    float wstep = 6.28318530717958647692f / (float)m;
    #pragma unroll
    for (int i = 0; i < 8; ++i) {
      int idx = tid + i * 512;
      int j   = idx & (half - 1);
      int i0  = 2 * idx - j;
      int i1  = i0 + half;
      float2 a = z[i0];
      float2 b = z[i1];
      float sn, cs; __sincosf(wstep * (float)j, &sn, &cs);
      float2 bw = make_float2(b.x*cs - b.y*sn, b.x*sn + b.y*cs);
      z[i0] = make_float2(a.x + bw.x, a.y + bw.y);
      z[i1] = make_float2(a.x - bw.x, a.y - bw.y);
    }
    __syncthreads();
  }

  float Dv = Dp[0];
  float* o0 = out + row0 * SEQ_L;
  float* o1 = o0 + SEQ_L;
  #pragma unroll
  for (int i = 0; i < 8; ++i) {
    int t = tid + i * 512;
    float2 w = z[t];
    o0[t] = w.x + Dv * u0[t];
    o1[t] = w.y + Dv * u1[t];
  }
}

// ---------------------------------------------------------------- launch
extern "C" void kernel_launch(void* const* d_in, const int* in_sizes, int n_in,
                              void* d_out, int out_size, void* d_ws, size_t ws_size,
                              hipStream_t stream) {
  const float* u      = (const float*)d_in[0];
  const float* Lam_ri = (const float*)d_in[1];
  const float* p_ri   = (const float*)d_in[2];
  const float* q_ri   = (const float*)d_in[3];
  const float* Vc_ri  = (const float*)d_in[4];
  const float* Ct_ri  = (const float*)d_in[5];
  const float* Bp     = (const float*)d_in[6];
  const float* Dp     = (const float*)d_in[7];
  const float* ls     = (const float*)d_in[8];

  char* ws = (char*)d_ws;
  float2*  atroots = (float2*) (ws);                 // 32768 B
  float*   Kt      = (float*)  (ws + 32768);         // 16384 B
  float2*  kf_br   = (float2*) (ws + 49152);         // 65536 B
  double2* lam     = (double2*)(ws + 114688);        // 1024 B each
  double2* ctB     = (double2*)(ws + 115712);
  double2* ctp     = (double2*)(ws + 116736);
  double2* qB      = (double2*)(ws + 117760);
  double2* qp      = (double2*)(ws + 118784);
  double*  stepp   = (double*) (ws + 119808);

  k_prep<<<dim3(1), dim3(64), 0, stream>>>(Lam_ri, p_ri, q_ri, Vc_ri, Ct_ri, Bp, ls,
                                           lam, ctB, ctp, qB, qp, stepp);
  k_atroots<<<dim3(16), dim3(256), 0, stream>>>(lam, ctB, ctp, qB, qp, stepp, atroots);
  k_kt<<<dim3(512), dim3(512), 0, stream>>>(atroots, Kt);
  k_kf<<<dim3(1024), dim3(512), 0, stream>>>(Kt, kf_br);
  k_conv<<<dim3(NROWS/2), dim3(512), 0, stream>>>(u, kf_br, Dp, (float*)d_out);
}

// Round 2
// 255.096 us; speedup vs baseline: 1.5168x; 1.5168x over previous
//
#include <hip/hip_runtime.h>
#include <math.h>

// S4 conv: y = irfft(rfft(u,8192)*rfft(K,8192))[:4096] + D*u ; K shared by all rows.
// Round 2: radix-4 FFT (6 stages + trivial radix-2), fused ends, LDS XOR swizzle.

#define SEQ_L 4096
#define NFFT  8192
#define NST   64
#define NROWS 8192
#define TWO_PI 6.28318530717958647692f

__device__ __forceinline__ double2 dcmul(double2 a, double2 b) {
  return make_double2(a.x*b.x - a.y*b.y, a.x*b.y + a.y*b.x);
}
__device__ __forceinline__ float2 cmul(float2 a, float2 b) {
  return make_float2(a.x*b.x - a.y*b.y, a.x*b.y + a.y*b.x);
}
__device__ __forceinline__ float2 cadd(float2 a, float2 b) { return make_float2(a.x+b.x, a.y+b.y); }
__device__ __forceinline__ float2 csub(float2 a, float2 b) { return make_float2(a.x-b.x, a.y-b.y); }
__device__ __forceinline__ int swz(int e) { return e ^ ((e >> 4) & 15); }

// ---------------------------------------------------------------- k_prep (fp64 setup)
__global__ __launch_bounds__(64) void k_prep(
    const float* __restrict__ Lam_ri, const float* __restrict__ p_ri,
    const float* __restrict__ q_ri,  const float* __restrict__ Vc_ri,
    const float* __restrict__ Ct_ri, const float* __restrict__ Bp,
    const float* __restrict__ log_step,
    double2* __restrict__ lam, double2* __restrict__ ctB,
    double2* __restrict__ ctp, double2* __restrict__ qB,
    double2* __restrict__ qp,  double* __restrict__ stepp) {
  int n = threadIdx.x;
  if (n >= NST) return;
  double lr = Lam_ri[2*n], li = Lam_ri[2*n+1];
  double pr = p_ri[2*n],  pi = p_ri[2*n+1];
  double qr = q_ri[2*n],  qi = q_ri[2*n+1];
  double cr = Ct_ri[2*n], ci = Ct_ri[2*n+1];
  double br = 0.0, bi = 0.0;
  for (int m = 0; m < NST; ++m) {
    double b = (double)Bp[m];
    br += (double)Vc_ri[2*(n*NST+m)]   * b;
    bi += (double)Vc_ri[2*(n*NST+m)+1] * b;
  }
  lam[n] = make_double2(lr, li);
  ctB[n] = make_double2(cr*br + ci*bi, cr*bi - ci*br);
  ctp[n] = make_double2(cr*pr + ci*pi, cr*pi - ci*pr);
  qB[n]  = make_double2(qr*br + qi*bi, qr*bi - qi*br);
  qp[n]  = make_double2(qr*pr + qi*pi, qr*pi - qi*pr);
  if (n == 0) *stepp = exp((double)log_step[0]);
}

// ---------------------------------------------------------------- k_atroots (fp64)
__global__ __launch_bounds__(256) void k_atroots(
    const double2* __restrict__ lam, const double2* __restrict__ ctB,
    const double2* __restrict__ ctp, const double2* __restrict__ qB,
    const double2* __restrict__ qp,  const double* __restrict__ stepp,
    float2* __restrict__ atroots) {
  int l = blockIdx.x * blockDim.x + threadIdx.x;
  if (l >= SEQ_L) return;
  double step = *stepp;
  double ang = -2.0 * M_PI * (double)l / (double)SEQ_L;
  double sn, cs;
  sincos(ang, &sn, &cs);
  double2 onem = make_double2(1.0 - cs, -sn);
  double2 onep = make_double2(1.0 + cs,  sn);
  double den = onep.x*onep.x + onep.y*onep.y;
  double2 ip = make_double2(onep.x/den, -onep.y/den);
  double2 g  = dcmul(onem, ip);
  double tw = 2.0 / step;
  g.x *= tw; g.y *= tw;
  double2 cc = make_double2(2.0*ip.x, 2.0*ip.y);
  double2 k00 = make_double2(0,0), k01 = make_double2(0,0);
  double2 k10 = make_double2(0,0), k11 = make_double2(0,0);
  for (int n = 0; n < NST; ++n) {
    double2 L = lam[n];
    double2 d = make_double2(g.x - L.x, g.y - L.y);
    double dd = d.x*d.x + d.y*d.y;
    double2 inv = make_double2(d.x/dd, -d.y/dd);
    double2 v;
    v = ctB[n]; k00.x += v.x*inv.x - v.y*inv.y; k00.y += v.x*inv.y + v.y*inv.x;
    v = ctp[n]; k01.x += v.x*inv.x - v.y*inv.y; k01.y += v.x*inv.y + v.y*inv.x;
    v = qB[n];  k10.x += v.x*inv.x - v.y*inv.y; k10.y += v.x*inv.y + v.y*inv.x;
    v = qp[n];  k11.x += v.x*inv.x - v.y*inv.y; k11.y += v.x*inv.y + v.y*inv.x;
  }
  double2 k11p = make_double2(1.0 + k11.x, k11.y);
  double2 num  = dcmul(k01, k10);
  double dd2 = k11p.x*k11p.x + k11p.y*k11p.y;
  double2 t = make_double2((num.x*k11p.x + num.y*k11p.y)/dd2,
                           (num.y*k11p.x - num.x*k11p.y)/dd2);
  double2 inner = make_double2(k00.x - t.x, k00.y - t.y);
  double2 at = dcmul(cc, inner);
  atroots[l] = make_float2((float)at.x, (float)at.y);
}

// ---------------------------------------------------------------- k_kt
// K[t] = Re((1/4096) sum_l at[l] e^{+2pi i l t/4096}), one wave per t
__global__ __launch_bounds__(512) void k_kt(const float2* __restrict__ atroots,
                                            float* __restrict__ Kt) {
  int gid  = blockIdx.x * 512 + threadIdx.x;
  int t    = gid >> 6;
  int lane = gid & 63;
  float acc = 0.f;
  for (int l = lane; l < SEQ_L; l += 64) {
    int ph = (l * t) & (SEQ_L - 1);
    float a = (float)ph * (TWO_PI / (float)SEQ_L);
    float sn, cs; __sincosf(a, &sn, &cs);
    float2 v = atroots[l];
    acc += v.x*cs - v.y*sn;
  }
  for (int off = 32; off > 0; off >>= 1) acc += __shfl_down(acc, off, 64);
  if (lane == 0) Kt[t] = acc * (1.0f / (float)SEQ_L);
}

// ------------------------------------------------------ radix-4 stage helpers
// forward DIF butterfly, sub-size M, Q=M/4, twiddle w = exp(-2pi i j / M)
template <int M>
__device__ __forceinline__ void fwd_stage(float2* z, int tid) {
  const int Q = M >> 2;
  const float wstep = -TWO_PI / (float)M;
  #pragma unroll
  for (int i = 0; i < 4; ++i) {
    int idx = tid + i * 512;            // [0, 2048)
    int j   = idx & (Q - 1);
    int base = 4 * idx - 3 * j;         // g*M + j
    float2 a0 = z[swz(base)];
    float2 a1 = z[swz(base + Q)];
    float2 a2 = z[swz(base + 2*Q)];
    float2 a3 = z[swz(base + 3*Q)];
    float2 t0 = cadd(a0, a2), t1 = csub(a0, a2);
    float2 t2 = cadd(a1, a3), t3 = csub(a1, a3);
    float sn, cs; __sincosf(wstep * (float)j, &sn, &cs);
    float2 w1 = make_float2(cs, sn);
    float2 w2 = cmul(w1, w1);
    float2 w3 = cmul(w2, w1);
    float2 y0 = cadd(t0, t2);
    float2 y1 = make_float2(t1.x + t3.y, t1.y - t3.x);   // t1 - i t3
    float2 y2 = csub(t0, t2);
    float2 y3 = make_float2(t1.x - t3.y, t1.y + t3.x);   // t1 + i t3
    z[swz(base)]       = y0;
    z[swz(base + Q)]   = cmul(y1, w1);
    z[swz(base + 2*Q)] = cmul(y2, w2);
    z[swz(base + 3*Q)] = cmul(y3, w3);
  }
}

// inverse of fwd_stage<M> (conj twiddles, transposed butterfly); no 1/4 (folded in Kf)
template <int M>
__device__ __forceinline__ void inv_stage(float2* z, int tid) {
  const int Q = M >> 2;
  const float wstep = -TWO_PI / (float)M;
  #pragma unroll
  for (int i = 0; i < 4; ++i) {
    int idx = tid + i * 512;
    int j   = idx & (Q - 1);
    int base = 4 * idx - 3 * j;
    float2 y0 = z[swz(base)];
    float2 y1 = z[swz(base + Q)];
    float2 y2 = z[swz(base + 2*Q)];
    float2 y3 = z[swz(base + 3*Q)];
    float sn, cs; __sincosf(wstep * (float)j, &sn, &cs);
    float2 c1 = make_float2(cs, -sn);                    // conj(w^j)
    float2 c2 = cmul(c1, c1);
    float2 c3 = cmul(c2, c1);
    float2 u0 = y0;
    float2 u1 = cmul(y1, c1);
    float2 u2 = cmul(y2, c2);
    float2 u3 = cmul(y3, c3);
    float2 s0 = cadd(u0, u2), s1 = csub(u0, u2);
    float2 s2 = cadd(u1, u3), s3 = csub(u1, u3);
    z[swz(base)]       = cadd(s0, s2);
    z[swz(base + Q)]   = make_float2(s1.x - s3.y, s1.y + s3.x);  // s1 + i s3
    z[swz(base + 2*Q)] = csub(s0, s2);
    z[swz(base + 3*Q)] = make_float2(s1.x + s3.y, s1.y - s3.x);  // s1 - i s3
  }
}

// ---------------------------------------------------------------- k_kf
// One block: run the SAME scrambled forward FFT on [K, 0pad] -> kf (scrambled order,
// scaled by 1/8192). Guarantees order consistency with k_conv by construction.
__global__ __launch_bounds__(512) void k_kf(const float* __restrict__ Kt,
                                            float2* __restrict__ kf) {
  __shared__ float2 z[NFFT];
  int tid = threadIdx.x;
  #pragma unroll
  for (int i = 0; i < 16; ++i) {
    int t = tid + i * 512;
    z[swz(t)] = make_float2(t < SEQ_L ? Kt[t] : 0.f, 0.f);
  }
  __syncthreads();
  fwd_stage<8192>(z, tid); __syncthreads();
  fwd_stage<2048>(z, tid); __syncthreads();
  fwd_stage<512>(z, tid);  __syncthreads();
  fwd_stage<128>(z, tid);  __syncthreads();
  fwd_stage<32>(z, tid);   __syncthreads();
  fwd_stage<8>(z, tid);    __syncthreads();
  #pragma unroll
  for (int i = 0; i < 8; ++i) {            // final radix-2 (twiddle = 1)
    int t = tid + i * 512;
    float2 a = z[swz(2*t)], b = z[swz(2*t+1)];
    z[swz(2*t)]   = cadd(a, b);
    z[swz(2*t+1)] = csub(a, b);
  }
  __syncthreads();
  const float inv_n = 1.0f / (float)NFFT;
  #pragma unroll
  for (int i = 0; i < 16; ++i) {
    int t = tid + i * 512;
    float2 v = z[swz(t)];
    kf[t] = make_float2(v.x * inv_n, v.y * inv_n);
  }
}

// ---------------------------------------------------------------- k_conv
__global__ __launch_bounds__(512) void k_conv(const float* __restrict__ u,
                                              const float2* __restrict__ kf,
                                              const float* __restrict__ Dp,
                                              float* __restrict__ out) {
  __shared__ float2 z[NFFT];
  int tid = threadIdx.x;
  size_t row0 = (size_t)blockIdx.x * 2;
  const float* ru0 = u + row0 * SEQ_L;
  const float* ru1 = ru0 + SEQ_L;
  const float wstep0 = -TWO_PI / (float)NFFT;

  // fused: global load + forward stage M=8192 with x2=x3=0 (zero padding)
  #pragma unroll
  for (int i = 0; i < 4; ++i) {
    int j = tid + i * 512;                  // [0, 2048)
    float2 x0 = make_float2(ru0[j],        ru1[j]);
    float2 x1 = make_float2(ru0[j + 2048], ru1[j + 2048]);
    float sn, cs; __sincosf(wstep0 * (float)j, &sn, &cs);
    float2 w1 = make_float2(cs, sn);
    float2 w2 = cmul(w1, w1);
    float2 w3 = cmul(w2, w1);
    float2 y0 = cadd(x0, x1);
    float2 y1 = make_float2(x0.x + x1.y, x0.y - x1.x);   // x0 - i x1
    float2 y2 = csub(x0, x1);
    float2 y3 = make_float2(x0.x - x1.y, x0.y + x1.x);   // x0 + i x1
    z[swz(j)]        = y0;
    z[swz(j + 2048)] = cmul(y1, w1);
    z[swz(j + 4096)] = cmul(y2, w2);
    z[swz(j + 6144)] = cmul(y3, w3);
  }
  __syncthreads();
  fwd_stage<2048>(z, tid); __syncthreads();
  fwd_stage<512>(z, tid);  __syncthreads();
  fwd_stage<128>(z, tid);  __syncthreads();
  fwd_stage<32>(z, tid);   __syncthreads();
  fwd_stage<8>(z, tid);    __syncthreads();

  // fused: forward radix-2 (w=1) + pointwise *Kf + inverse radix-2
  const float4* kf4 = (const float4*)kf;
  #pragma unroll
  for (int i = 0; i < 8; ++i) {
    int t = tid + i * 512;                  // [0, 4096)
    float2 a = z[swz(2*t)], b = z[swz(2*t+1)];
    float2 s = cadd(a, b), d = csub(a, b);
    float4 kk = kf4[t];
    s = cmul(s, make_float2(kk.x, kk.y));
    d = cmul(d, make_float2(kk.z, kk.w));
    z[swz(2*t)]   = cadd(s, d);
    z[swz(2*t+1)] = csub(s, d);
  }
  __syncthreads();
  inv_stage<8>(z, tid);    __syncthreads();
  inv_stage<32>(z, tid);   __syncthreads();
  inv_stage<128>(z, tid);  __syncthreads();
  inv_stage<512>(z, tid);  __syncthreads();
  inv_stage<2048>(z, tid); __syncthreads();

  // fused: inverse stage M=8192 + epilogue store (only first 4096 outputs kept)
  float Dv = Dp[0];
  float* o0 = out + row0 * SEQ_L;
  float* o1 = o0 + SEQ_L;
  #pragma unroll
  for (int i = 0; i < 4; ++i) {
    int j = tid + i * 512;                  // [0, 2048)
    float2 y0 = z[swz(j)];
    float2 y1 = z[swz(j + 2048)];
    float2 y2 = z[swz(j + 4096)];
    float2 y3 = z[swz(j + 6144)];
    float sn, cs; __sincosf(wstep0 * (float)j, &sn, &cs);
    float2 c1 = make_float2(cs, -sn);
    float2 c2 = cmul(c1, c1);
    float2 c3 = cmul(c2, c1);
    float2 u1c = cmul(y1, c1);
    float2 u2c = cmul(y2, c2);
    float2 u3c = cmul(y3, c3);
    float2 s0 = cadd(y0, u2c), s1 = csub(y0, u2c);
    float2 s2 = cadd(u1c, u3c), s3 = csub(u1c, u3c);
    float2 x0 = cadd(s0, s2);                                  // output pos j
    float2 x1 = make_float2(s1.x - s3.y, s1.y + s3.x);         // output pos j+2048
    o0[j]        = x0.x + Dv * ru0[j];
    o1[j]        = x0.y + Dv * ru1[j];
    o0[j + 2048] = x1.x + Dv * ru0[j + 2048];
    o1[j + 2048] = x1.y + Dv * ru1[j + 2048];
  }
}

// ---------------------------------------------------------------- launch
extern "C" void kernel_launch(void* const* d_in, const int* in_sizes, int n_in,
                              void* d_out, int out_size, void* d_ws, size_t ws_size,
                              hipStream_t stream) {
  const float* u      = (const float*)d_in[0];
  const float* Lam_ri = (const float*)d_in[1];
  const float* p_ri   = (const float*)d_in[2];
  const float* q_ri   = (const float*)d_in[3];
  const float* Vc_ri  = (const float*)d_in[4];
  const float* Ct_ri  = (const float*)d_in[5];
  const float* Bp     = (const float*)d_in[6];
  const float* Dp     = (const float*)d_in[7];
  const float* ls     = (const float*)d_in[8];

  char* ws = (char*)d_ws;
  float2*  atroots = (float2*) (ws);                 // 32768 B
  float*   Kt      = (float*)  (ws + 32768);         // 16384 B
  float2*  kf      = (float2*) (ws + 49152);         // 65536 B (scrambled, /8192)
  double2* lam     = (double2*)(ws + 114688);
  double2* ctB     = (double2*)(ws + 115712);
  double2* ctp     = (double2*)(ws + 116736);
  double2* qB      = (double2*)(ws + 117760);
  double2* qp      = (double2*)(ws + 118784);
  double*  stepp   = (double*) (ws + 119808);

  k_prep<<<dim3(1), dim3(64), 0, stream>>>(Lam_ri, p_ri, q_ri, Vc_ri, Ct_ri, Bp, ls,
                                           lam, ctB, ctp, qB, qp, stepp);
  k_atroots<<<dim3(16), dim3(256), 0, stream>>>(lam, ctB, ctp, qB, qp, stepp, atroots);
  k_kt<<<dim3(512), dim3(512), 0, stream>>>(atroots, Kt);
  k_kf<<<dim3(1), dim3(512), 0, stream>>>(Kt, kf);
  k_conv<<<dim3(NROWS/2), dim3(512), 0, stream>>>(u, kf, Dp, (float*)d_out);
}

// Round 3
// 251.383 us; speedup vs baseline: 1.5392x; 1.0148x over previous
//
#include <hip/hip_runtime.h>
#include <math.h>

// S4 conv: y = irfft(rfft(u,8192)*rfft(K,8192))[:4096] + D*u ; K shared by all rows.
// Round 3: register-resident FFT. 8192 = 16*16*16*2. Each thread owns 16 complex
// values; three radix-16 stages in registers + final radix-2 via shfl_xor(1).
// Only 2 LDS exchanges per direction (vs 13 passes in round 2), XOR-swizzled
// conflict-free. Inverse = exact per-stage inverses in reverse order, so any
// fixed output permutation cancels; Kf produced by the identical forward path.

#define SEQ_L 4096
#define NFFT  8192
#define NST   64
#define NROWS 8192
#define TWO_PI 6.28318530717958647692f

typedef float2 cf;

__device__ __forceinline__ cf cmul(cf a, cf b){ return make_float2(a.x*b.x - a.y*b.y, a.x*b.y + a.y*b.x); }
__device__ __forceinline__ cf cadd(cf a, cf b){ return make_float2(a.x+b.x, a.y+b.y); }
__device__ __forceinline__ cf csub(cf a, cf b){ return make_float2(a.x-b.x, a.y-b.y); }
__device__ __forceinline__ double2 dcmul(double2 a, double2 b) {
  return make_double2(a.x*b.x - a.y*b.y, a.x*b.y + a.y*b.x);
}
// LDS XOR swizzle on float2 index (bank = low5 ^ bits[9:5] -> all our patterns <=2 addr/bank)
__device__ __forceinline__ int sw(int p){ return p ^ ((p >> 5) & 31); }

// multiply a by (ce, S*se)
template<int S>
__device__ __forceinline__ cf twc(cf a, float ce, float se){
  const float s = (S < 0) ? -se : se;
  return make_float2(a.x*ce - a.y*s, a.x*s + a.y*ce);
}

// radix-4 in place; omega4 = (0, S)
template<int S>
__device__ __forceinline__ void r4(cf& a0, cf& a1, cf& a2, cf& a3){
  cf t0 = cadd(a0,a2), t1 = csub(a0,a2);
  cf t2 = cadd(a1,a3), t3 = csub(a1,a3);
  cf w = (S < 0) ? make_float2(t3.y, -t3.x) : make_float2(-t3.y, t3.x);  // omega4*t3
  a0 = cadd(t0,t2); a2 = csub(t0,t2);
  a1 = cadd(t1,w);  a3 = csub(t1,w);
}

// 16-point DFT in place (natural order in/out), sign S. ZHI: x[8..15] known zero.
template<int S, bool ZHI>
__device__ __forceinline__ void dft16(cf x[16]){
  const float E1c = 0.92387953251128674f, E1s = 0.38268343236508978f;  // 2pi/16
  const float E2c = 0.70710678118654752f, E2s = 0.70710678118654752f;
  const float E3c = 0.38268343236508978f, E3s = 0.92387953251128674f;
  const float E6c = -0.70710678118654752f, E6s = 0.70710678118654752f;
  const float E9c = -0.92387953251128674f, E9s = -0.38268343236508978f;
  cf b[16];
  #pragma unroll
  for (int n = 0; n < 4; ++n) {
    cf t0, t1, t2, t3;
    if (ZHI) { t0 = x[n]; t1 = x[n]; t2 = x[n+4]; t3 = x[n+4]; }
    else {
      t0 = cadd(x[n], x[n+8]);  t1 = csub(x[n], x[n+8]);
      t2 = cadd(x[n+4], x[n+12]); t3 = csub(x[n+4], x[n+12]);
    }
    cf w = (S < 0) ? make_float2(t3.y, -t3.x) : make_float2(-t3.y, t3.x);
    cf A0 = cadd(t0,t2), A2 = csub(t0,t2);
    cf A1 = cadd(t1,w),  A3 = csub(t1,w);
    if (n == 0) { b[0]  = A0; b[4]  = A1; b[8]  = A2; b[12] = A3; }
    else if (n == 1) {
      b[1]  = A0; b[5]  = twc<S>(A1, E1c, E1s);
      b[9]  = twc<S>(A2, E2c, E2s); b[13] = twc<S>(A3, E3c, E3s);
    } else if (n == 2) {
      b[2]  = A0; b[6]  = twc<S>(A1, E2c, E2s);
      b[10] = (S < 0) ? make_float2(A2.y, -A2.x) : make_float2(-A2.y, A2.x);  // *omega16^4
      b[14] = twc<S>(A3, E6c, E6s);
    } else {
      b[3]  = A0; b[7]  = twc<S>(A1, E3c, E3s);
      b[11] = twc<S>(A2, E6c, E6s); b[15] = twc<S>(A3, E9c, E9s);
    }
  }
  #pragma unroll
  for (int k0 = 0; k0 < 4; ++k0) {
    cf a0 = b[k0*4+0], a1 = b[k0*4+1], a2 = b[k0*4+2], a3 = b[k0*4+3];
    r4<S>(a0,a1,a2,a3);
    x[k0+0] = a0; x[k0+4] = a1; x[k0+8] = a2; x[k0+12] = a3;
  }
}

// x[k] *= w^k for k=1..15, w = (cs, sn)
__device__ __forceinline__ void twiddle_chain(cf x[16], float cs, float sn){
  cf w = make_float2(cs, sn);
  cf wk = w;
  x[1] = cmul(x[1], wk);
  #pragma unroll
  for (int k = 2; k < 16; ++k) { wk = cmul(wk, w); x[k] = cmul(x[k], wk); }
}

// stage-3 twiddle: x[k] *= omega32^{S * t00 * k}; t00 in {0,1}; constants.
__device__ __forceinline__ constexpr float c32t(int k){
  return (k==0)?1.f:(k==1)?0.98078528040323044913f:(k==2)?0.92387953251128675613f:
         (k==3)?0.83146961230254523708f:(k==4)?0.70710678118654752440f:
         (k==5)?0.55557023301960222474f:(k==6)?0.38268343236508977173f:
         (k==7)?0.19509032201612826785f:(k==8)?0.f:(k==9)?-0.19509032201612826785f:
         (k==10)?-0.38268343236508977173f:(k==11)?-0.55557023301960222474f:
         (k==12)?-0.70710678118654752440f:(k==13)?-0.83146961230254523708f:
         (k==14)?-0.92387953251128675613f:-0.98078528040323044913f;
}
__device__ __forceinline__ constexpr float s32t(int k){
  return (k==0)?0.f:(k==1)?0.19509032201612826785f:(k==2)?0.38268343236508977173f:
         (k==3)?0.55557023301960222474f:(k==4)?0.70710678118654752440f:
         (k==5)?0.83146961230254523708f:(k==6)?0.92387953251128675613f:
         (k==7)?0.98078528040323044913f:(k==8)?1.f:(k==9)?0.98078528040323044913f:
         (k==10)?0.92387953251128675613f:(k==11)?0.83146961230254523708f:
         (k==12)?0.70710678118654752440f:(k==13)?0.55557023301960222474f:
         (k==14)?0.38268343236508977173f:0.19509032201612826785f;
}
template<int S>
__device__ __forceinline__ void tw32_t00(cf x[16], int t00){
  #pragma unroll
  for (int k = 1; k < 16; ++k) {
    float ce = t00 ? c32t(k) : 1.f;
    float se = t00 ? ((S < 0) ? -s32t(k) : s32t(k)) : 0.f;
    cf a = x[k];
    x[k] = make_float2(a.x*ce - a.y*se, a.x*se + a.y*ce);
  }
}

// radix-2 across lane pairs (self-inverse up to factor 2)
__device__ __forceinline__ void r2_shfl(cf x[16], int tid){
  const float sgn = (tid & 1) ? -1.f : 1.f;
  #pragma unroll
  for (int k = 0; k < 16; ++k) {
    float ox = __shfl_xor(x[k].x, 1, 64);
    float oy = __shfl_xor(x[k].y, 1, 64);
    x[k].x = ox + sgn * x[k].x;
    x[k].y = oy + sgn * x[k].y;
  }
}

// ---- full forward: input x[m] = z[tid + 512 m]; output: permuted spectrum,
// slot k3 of thread tid = bin (k1 + 16 k2 + 256 k3 + 4096 t00).
template<bool ZHI>
__device__ __forceinline__ void fwd_all(cf x[16], cf* lds, int tid){
  // stage 1: DFT16 over m (stride 512), twiddle w8192^{tid*k1}
  dft16<-1, ZHI>(x);
  { float sn, cs; __sincosf(-TWO_PI * (float)tid / (float)NFFT, &sn, &cs);
    twiddle_chain(x, cs, sn); }
  // exchange 1
  #pragma unroll
  for (int k1 = 0; k1 < 16; ++k1) lds[sw(k1*512 + tid)] = x[k1];
  __syncthreads();
  { int k1 = tid >> 5, t0 = tid & 31;
    #pragma unroll
    for (int r = 0; r < 16; ++r) x[r] = lds[sw(k1*512 + t0 + 32*r)];
  }
  // stage 2: DFT16 over r (stride 32), twiddle w512^{t0*k2}
  dft16<-1, false>(x);
  { float sn, cs; __sincosf(-TWO_PI * (float)(tid & 31) / 512.f, &sn, &cs);
    twiddle_chain(x, cs, sn); }
  __syncthreads();
  // exchange 2
  { int k1 = tid >> 5, t0 = tid & 31;
    #pragma unroll
    for (int k2 = 0; k2 < 16; ++k2) lds[sw(k1*512 + k2*32 + t0)] = x[k2];
  }
  __syncthreads();
  { int k1 = tid >> 5, k2 = (tid >> 1) & 15, t00 = tid & 1;
    #pragma unroll
    for (int r = 0; r < 16; ++r) x[r] = lds[sw(k1*512 + k2*32 + t00 + 2*r)];
  }
  // stage 3: DFT16 over r (stride 2), twiddle w32^{t00*k3}
  dft16<-1, false>(x);
  tw32_t00<-1>(x, tid & 1);
  // stage 4: radix-2 across t00 (lane pairs)
  r2_shfl(x, tid);
}

// ---- full inverse (un-normalized by 8192; 1/8192 folded into kf)
__device__ __forceinline__ void inv_all(cf x[16], cf* lds, int tid){
  r2_shfl(x, tid);                       // inverse radix-2 (x2)
  tw32_t00<1>(x, tid & 1);               // conj twiddle
  dft16<1, false>(x);                    // inverse stage 3 (x16)
  __syncthreads();
  // inverse exchange 2: write stage-3 pattern, read stage-2 pattern
  { int k1 = tid >> 5, k2 = (tid >> 1) & 15, t00 = tid & 1;
    #pragma unroll
    for (int r = 0; r < 16; ++r) lds[sw(k1*512 + k2*32 + t00 + 2*r)] = x[r];
  }
  __syncthreads();
  { int k1 = tid >> 5, t0 = tid & 31;
    #pragma unroll
    for (int k2 = 0; k2 < 16; ++k2) x[k2] = lds[sw(k1*512 + k2*32 + t0)];
  }
  { float sn, cs; __sincosf(TWO_PI * (float)(tid & 31) / 512.f, &sn, &cs);
    twiddle_chain(x, cs, sn); }
  dft16<1, false>(x);                    // inverse stage 2 (x16)
  __syncthreads();
  // inverse exchange 1
  { int k1 = tid >> 5, t0 = tid & 31;
    #pragma unroll
    for (int r = 0; r < 16; ++r) lds[sw(k1*512 + t0 + 32*r)] = x[r];
  }
  __syncthreads();
  #pragma unroll
  for (int k1 = 0; k1 < 16; ++k1) x[k1] = lds[sw(k1*512 + tid)];
  { float sn, cs; __sincosf(TWO_PI * (float)tid / (float)NFFT, &sn, &cs);
    twiddle_chain(x, cs, sn); }
  dft16<1, false>(x);                    // inverse stage 1 (x16)
  // x[m] = 8192 * conv_result[tid + 512 m]
}

// ---------------------------------------------------------------- k_at (fp64 setup, fused prep)
__global__ __launch_bounds__(256) void k_at(
    const float* __restrict__ Lam_ri, const float* __restrict__ p_ri,
    const float* __restrict__ q_ri,  const float* __restrict__ Vc_ri,
    const float* __restrict__ Ct_ri, const float* __restrict__ Bp,
    const float* __restrict__ log_step, float2* __restrict__ atroots) {
  __shared__ double2 lam[NST], ctB[NST], ctp[NST], qB[NST], qp[NST];
  __shared__ double stepd;
  int tx = threadIdx.x;
  if (tx < NST) {
    int n = tx;
    double lr = Lam_ri[2*n], li = Lam_ri[2*n+1];
    double pr = p_ri[2*n],  pi = p_ri[2*n+1];
    double qr = q_ri[2*n],  qi = q_ri[2*n+1];
    double cr = Ct_ri[2*n], ci = Ct_ri[2*n+1];
    double br = 0.0, bi = 0.0;
    for (int m = 0; m < NST; ++m) {
      double b = (double)Bp[m];
      br += (double)Vc_ri[2*(n*NST+m)]   * b;
      bi += (double)Vc_ri[2*(n*NST+m)+1] * b;
    }
    lam[n] = make_double2(lr, li);
    ctB[n] = make_double2(cr*br + ci*bi, cr*bi - ci*br);
    ctp[n] = make_double2(cr*pr + ci*pi, cr*pi - ci*pr);
    qB[n]  = make_double2(qr*br + qi*bi, qr*bi - qi*br);
    qp[n]  = make_double2(qr*pr + qi*pi, qr*pi - qi*pr);
  }
  if (tx == 0) stepd = exp((double)log_step[0]);
  __syncthreads();
  int l = blockIdx.x * 256 + tx;
  double ang = -2.0 * M_PI * (double)l / (double)SEQ_L;
  double sn, cs;
  sincos(ang, &sn, &cs);
  double2 onem = make_double2(1.0 - cs, -sn);
  double2 onep = make_double2(1.0 + cs,  sn);
  double den = onep.x*onep.x + onep.y*onep.y;
  double2 ip = make_double2(onep.x/den, -onep.y/den);   // 1/(1+Omega)
  double2 g  = dcmul(onem, ip);
  double tw = 2.0 / stepd;
  g.x *= tw; g.y *= tw;
  double2 cc = make_double2(2.0*ip.x, 2.0*ip.y);        // 2/(1+Omega)
  double2 k00 = make_double2(0,0), k01 = make_double2(0,0);
  double2 k10 = make_double2(0,0), k11 = make_double2(0,0);
  for (int n = 0; n < NST; ++n) {
    double2 L = lam[n];
    double2 d = make_double2(g.x - L.x, g.y - L.y);
    double dd = d.x*d.x + d.y*d.y;
    double2 inv = make_double2(d.x/dd, -d.y/dd);
    double2 v;
    v = ctB[n]; k00.x += v.x*inv.x - v.y*inv.y; k00.y += v.x*inv.y + v.y*inv.x;
    v = ctp[n]; k01.x += v.x*inv.x - v.y*inv.y; k01.y += v.x*inv.y + v.y*inv.x;
    v = qB[n];  k10.x += v.x*inv.x - v.y*inv.y; k10.y += v.x*inv.y + v.y*inv.x;
    v = qp[n];  k11.x += v.x*inv.x - v.y*inv.y; k11.y += v.x*inv.y + v.y*inv.x;
  }
  double2 k11p = make_double2(1.0 + k11.x, k11.y);
  double2 num  = dcmul(k01, k10);
  double dd2 = k11p.x*k11p.x + k11p.y*k11p.y;
  double2 t = make_double2((num.x*k11p.x + num.y*k11p.y)/dd2,
                           (num.y*k11p.x - num.x*k11p.y)/dd2);
  double2 inner = make_double2(k00.x - t.x, k00.y - t.y);
  double2 at = dcmul(cc, inner);
  atroots[l] = make_float2((float)at.x, (float)at.y);
}

// ---------------------------------------------------------------- k_kt (brute-force IDFT_4096, wave per t)
__global__ __launch_bounds__(512) void k_kt(const float2* __restrict__ atroots,
                                            float* __restrict__ Kt) {
  int gid  = blockIdx.x * 512 + threadIdx.x;
  int t    = gid >> 6;
  int lane = gid & 63;
  float acc = 0.f;
  for (int l = lane; l < SEQ_L; l += 64) {
    int ph = (l * t) & (SEQ_L - 1);
    float a = (float)ph * (TWO_PI / (float)SEQ_L);
    float sn, cs; __sincosf(a, &sn, &cs);
    float2 v = atroots[l];
    acc += v.x*cs - v.y*sn;
  }
  for (int off = 32; off > 0; off >>= 1) acc += __shfl_down(acc, off, 64);
  if (lane == 0) Kt[t] = acc * (1.0f / (float)SEQ_L);
}

// ---------------------------------------------------------------- k_kf (one block: forward on [K,0], scaled)
__global__ __launch_bounds__(512, 4) void k_kf(const float* __restrict__ Kt,
                                               cf* __restrict__ kf) {
  __shared__ cf lds[NFFT];
  int tid = threadIdx.x;
  cf x[16];
  #pragma unroll
  for (int m = 0; m < 8; ++m) x[m] = make_float2(Kt[tid + 512*m], 0.f);
  #pragma unroll
  for (int m = 8; m < 16; ++m) x[m] = make_float2(0.f, 0.f);
  fwd_all<true>(x, lds, tid);
  const float s = 1.f / (float)NFFT;
  #pragma unroll
  for (int k = 0; k < 16; ++k)
    kf[tid*16 + k] = make_float2(x[k].x * s, x[k].y * s);
}

// ---------------------------------------------------------------- k_conv
__global__ __launch_bounds__(512, 4) void k_conv(const float* __restrict__ u,
                                                 const cf* __restrict__ kf,
                                                 const float* __restrict__ Dp,
                                                 float* __restrict__ out) {
  __shared__ cf lds[NFFT];
  int tid = threadIdx.x;
  size_t row0 = (size_t)blockIdx.x * 2;
  const float* ru0 = u + row0 * SEQ_L;
  const float* ru1 = ru0 + SEQ_L;
  cf x[16];
  #pragma unroll
  for (int m = 0; m < 8; ++m) {
    int n = tid + 512*m;
    x[m] = make_float2(ru0[n], ru1[n]);
  }
  #pragma unroll
  for (int m = 8; m < 16; ++m) x[m] = make_float2(0.f, 0.f);

  fwd_all<true>(x, lds, tid);

  // pointwise multiply with Kf (same permuted order, includes 1/8192)
  const float4* kf4 = (const float4*)kf + (size_t)tid * 8;
  #pragma unroll
  for (int k = 0; k < 8; ++k) {
    float4 kk = kf4[k];
    x[2*k]   = cmul(x[2*k],   make_float2(kk.x, kk.y));
    x[2*k+1] = cmul(x[2*k+1], make_float2(kk.z, kk.w));
  }

  inv_all(x, lds, tid);

  float Dv = Dp[0];
  float* o0 = out + row0 * SEQ_L;
  float* o1 = o0 + SEQ_L;
  #pragma unroll
  for (int m = 0; m < 8; ++m) {
    int n = tid + 512*m;
    o0[n] = x[m].x + Dv * ru0[n];
    o1[n] = x[m].y + Dv * ru1[n];
  }
}

// ---------------------------------------------------------------- launch
extern "C" void kernel_launch(void* const* d_in, const int* in_sizes, int n_in,
                              void* d_out, int out_size, void* d_ws, size_t ws_size,
                              hipStream_t stream) {
  const float* u      = (const float*)d_in[0];
  const float* Lam_ri = (const float*)d_in[1];
  const float* p_ri   = (const float*)d_in[2];
  const float* q_ri   = (const float*)d_in[3];
  const float* Vc_ri  = (const float*)d_in[4];
  const float* Ct_ri  = (const float*)d_in[5];
  const float* Bp     = (const float*)d_in[6];
  const float* Dp     = (const float*)d_in[7];
  const float* ls     = (const float*)d_in[8];

  char* ws = (char*)d_ws;
  float2* atroots = (float2*)(ws);            // 32768 B
  float*  Kt      = (float*) (ws + 32768);    // 16384 B
  cf*     kf      = (cf*)    (ws + 49152);    // 65536 B (permuted order, /8192)

  k_at<<<dim3(SEQ_L/256), dim3(256), 0, stream>>>(Lam_ri, p_ri, q_ri, Vc_ri, Ct_ri, Bp, ls, atroots);
  k_kt<<<dim3(512), dim3(512), 0, stream>>>(atroots, Kt);
  k_kf<<<dim3(1), dim3(512), 0, stream>>>(Kt, kf);
  k_conv<<<dim3(NROWS/2), dim3(512), 0, stream>>>(u, kf, Dp, (float*)d_out);
}

// Round 4
// 204.264 us; speedup vs baseline: 1.8943x; 1.2307x over previous
//
#include <hip/hip_runtime.h>
#include <math.h>

// S4 conv: y = irfft(rfft(u,8192)*rfft(K,8192))[:4096] + D*u ; K shared by all rows.
// Round 4: 1024 threads x 8 cf/thread. 8192 = 8*8*8*8*2: four register DFT-8
// stages (3 swizzled LDS exchanges) + radix-2 via shfl_xor(1). Small per-thread
// state -> no scratch spill (round-3 failure: 274 MB of spill writebacks).

#define SEQ_L 4096
#define NFFT  8192
#define NST   64
#define NROWS 8192
#define TWO_PI 6.28318530717958647692f

typedef float2 cf;

__device__ __forceinline__ cf cmul(cf a, cf b){ return make_float2(a.x*b.x - a.y*b.y, a.x*b.y + a.y*b.x); }
__device__ __forceinline__ cf cadd(cf a, cf b){ return make_float2(a.x+b.x, a.y+b.y); }
__device__ __forceinline__ cf csub(cf a, cf b){ return make_float2(a.x-b.x, a.y-b.y); }
__device__ __forceinline__ double2 dcmul(double2 a, double2 b) {
  return make_double2(a.x*b.x - a.y*b.y, a.x*b.y + a.y*b.x);
}
// LDS XOR swizzle on float2 index: maps bits 4..7 into the bank-pair bits 0..3.
__device__ __forceinline__ int sw(int p){ return p ^ ((p >> 4) & 15); }

// radix-4 butterfly in place, natural bin order; omega4 = S*(-i) for S=-1 fwd
template<int S>
__device__ __forceinline__ void r4(cf& a0, cf& a1, cf& a2, cf& a3){
  cf t0 = cadd(a0,a2), t1 = csub(a0,a2);
  cf t2 = cadd(a1,a3), t3 = csub(a1,a3);
  cf w = (S < 0) ? make_float2(t3.y, -t3.x) : make_float2(-t3.y, t3.x);
  a0 = cadd(t0,t2); a2 = csub(t0,t2);
  a1 = cadd(t1,w);  a3 = csub(t1,w);
}

// 8-point DFT in place (natural in/out), sign S. ZHI: x[4..7] known zero (not read).
template<int S, bool ZHI>
__device__ __forceinline__ void dft8(cf x[8]){
  const float C = 0.70710678118654752f;
  cf e0,e1,e2,e3,o0,o1,o2,o3;
  if (ZHI) {
    // evens = (x0, x2, 0, 0); odds = (x1, x3, 0, 0)
    cf w  = (S<0)? make_float2(x[2].y,-x[2].x) : make_float2(-x[2].y,x[2].x);
    e0 = cadd(x[0],x[2]); e2 = csub(x[0],x[2]);
    e1 = cadd(x[0],w);    e3 = csub(x[0],w);
    cf w2 = (S<0)? make_float2(x[3].y,-x[3].x) : make_float2(-x[3].y,x[3].x);
    o0 = cadd(x[1],x[3]); o2 = csub(x[1],x[3]);
    o1 = cadd(x[1],w2);   o3 = csub(x[1],w2);
  } else {
    cf a0=x[0],a1=x[2],a2=x[4],a3=x[6];
    r4<S>(a0,a1,a2,a3);  e0=a0;e1=a1;e2=a2;e3=a3;
    cf b0=x[1],b1=x[3],b2=x[5],b3=x[7];
    r4<S>(b0,b1,b2,b3);  o0=b0;o1=b1;o2=b2;o3=b3;
  }
  x[0] = cadd(e0,o0); x[4] = csub(e0,o0);
  cf t1 = (S<0)? make_float2(C*(o1.x+o1.y), C*(o1.y-o1.x))
               : make_float2(C*(o1.x-o1.y), C*(o1.x+o1.y));
  x[1] = cadd(e1,t1); x[5] = csub(e1,t1);
  cf t2 = (S<0)? make_float2(o2.y,-o2.x) : make_float2(-o2.y,o2.x);
  x[2] = cadd(e2,t2); x[6] = csub(e2,t2);
  cf t3 = (S<0)? make_float2(C*(o3.y-o3.x), -C*(o3.x+o3.y))
               : make_float2(-C*(o3.x+o3.y), C*(o3.x-o3.y));
  x[3] = cadd(e3,t3); x[7] = csub(e3,t3);
}

// x[k] *= w^k, k=1..7, w = exp(i*th)
__device__ __forceinline__ void chain8(cf x[8], float th){
  float sn, cs; __sincosf(th, &sn, &cs);
  cf w = make_float2(cs, sn), wk = w;
  x[1] = cmul(x[1], wk);
  #pragma unroll
  for (int k = 2; k < 8; ++k) { wk = cmul(wk, w); x[k] = cmul(x[k], wk); }
}

// omega16 twiddle for stage D: x[d] *= omega16^{S*t000*d}; t000 in {0,1}
__device__ __forceinline__ constexpr float c16t(int d){
  return (d==1)?0.92387953251128675613f:(d==2)?0.70710678118654752440f:
         (d==3)?0.38268343236508977173f:(d==4)?0.f:
         (d==5)?-0.38268343236508977173f:(d==6)?-0.70710678118654752440f:
         -0.92387953251128675613f;
}
__device__ __forceinline__ constexpr float s16t(int d){
  return (d==1)?0.38268343236508977173f:(d==2)?0.70710678118654752440f:
         (d==3)?0.92387953251128675613f:(d==4)?1.f:
         (d==5)?0.92387953251128675613f:(d==6)?0.70710678118654752440f:
         0.38268343236508977173f;
}
template<int S>
__device__ __forceinline__ void tw16(cf x[8], int t000){
  #pragma unroll
  for (int d = 1; d < 8; ++d) {
    float ce = t000 ? c16t(d) : 1.f;
    float se = t000 ? ((S < 0) ? -s16t(d) : s16t(d)) : 0.f;
    cf a = x[d];
    x[d] = make_float2(a.x*ce - a.y*se, a.x*se + a.y*ce);
  }
}

// radix-2 across lane pairs (self-inverse up to factor 2)
__device__ __forceinline__ void r2_shfl(cf x[8], int tid){
  const float sgn = (tid & 1) ? -1.f : 1.f;
  #pragma unroll
  for (int k = 0; k < 8; ++k) {
    float ox = __shfl_xor(x[k].x, 1, 64);
    float oy = __shfl_xor(x[k].y, 1, 64);
    x[k].x = ox + sgn * x[k].x;
    x[k].y = oy + sgn * x[k].y;
  }
}

// ---- forward: x[m] = z[tid + 1024 m] -> permuted spectrum (slot d of thread tid)
template<bool ZHI>
__device__ __forceinline__ void fwd_all(cf x[8], cf* lds, int tid){
  int a1 = tid >> 7, t0 = tid & 127, t00 = tid & 15;
  int b2 = (tid >> 4) & 7, c3 = (tid >> 1) & 7, t000 = tid & 1;
  // stage A: DFT8 over m (stride 1024), twiddle w8192^{tid*a}
  dft8<-1, ZHI>(x);
  chain8(x, -TWO_PI * (float)tid / (float)NFFT);
  #pragma unroll
  for (int a = 0; a < 8; ++a) lds[sw(a*1024 + tid)] = x[a];
  __syncthreads();
  #pragma unroll
  for (int r = 0; r < 8; ++r) x[r] = lds[sw(a1*1024 + t0 + 128*r)];
  // stage B: DFT8 over r (stride 128), twiddle w1024^{t0*b}
  dft8<-1, false>(x);
  chain8(x, -TWO_PI * (float)t0 / 1024.f);
  __syncthreads();
  #pragma unroll
  for (int b = 0; b < 8; ++b) lds[sw(a1*1024 + b*128 + t0)] = x[b];
  __syncthreads();
  #pragma unroll
  for (int r = 0; r < 8; ++r) x[r] = lds[sw(a1*1024 + b2*128 + t00 + 16*r)];
  // stage C: DFT8 over r (stride 16), twiddle w128^{t00*c}
  dft8<-1, false>(x);
  chain8(x, -TWO_PI * (float)t00 / 128.f);
  __syncthreads();
  #pragma unroll
  for (int c = 0; c < 8; ++c) lds[sw(a1*1024 + b2*128 + c*16 + t00)] = x[c];
  __syncthreads();
  #pragma unroll
  for (int r = 0; r < 8; ++r) x[r] = lds[sw(a1*1024 + b2*128 + c3*16 + t000 + 2*r)];
  // stage D: DFT8 over r (stride 2), twiddle w16^{t000*d}
  dft8<-1, false>(x);
  tw16<-1>(x, t000);
  // stage E: radix-2 across t000 (lane pairs)
  r2_shfl(x, tid);
}

// ---- inverse (un-normalized by 8192; 1/8192 folded into kf)
__device__ __forceinline__ void inv_all(cf x[8], cf* lds, int tid){
  int a1 = tid >> 7, t0 = tid & 127, t00 = tid & 15;
  int b2 = (tid >> 4) & 7, c3 = (tid >> 1) & 7, t000 = tid & 1;
  r2_shfl(x, tid);
  tw16<1>(x, t000);
  dft8<1, false>(x);
  __syncthreads();
  #pragma unroll
  for (int r = 0; r < 8; ++r) lds[sw(a1*1024 + b2*128 + c3*16 + t000 + 2*r)] = x[r];
  __syncthreads();
  #pragma unroll
  for (int c = 0; c < 8; ++c) x[c] = lds[sw(a1*1024 + b2*128 + c*16 + t00)];
  chain8(x, TWO_PI * (float)t00 / 128.f);
  dft8<1, false>(x);
  __syncthreads();
  #pragma unroll
  for (int r = 0; r < 8; ++r) lds[sw(a1*1024 + b2*128 + t00 + 16*r)] = x[r];
  __syncthreads();
  #pragma unroll
  for (int b = 0; b < 8; ++b) x[b] = lds[sw(a1*1024 + b*128 + t0)];
  chain8(x, TWO_PI * (float)t0 / 1024.f);
  dft8<1, false>(x);
  __syncthreads();
  #pragma unroll
  for (int r = 0; r < 8; ++r) lds[sw(a1*1024 + t0 + 128*r)] = x[r];
  __syncthreads();
  #pragma unroll
  for (int a = 0; a < 8; ++a) x[a] = lds[sw(a*1024 + tid)];
  chain8(x, TWO_PI * (float)tid / (float)NFFT);
  dft8<1, false>(x);
  // x[m] = 8192 * conv[tid + 1024 m]
}

// ---------------------------------------------------------------- k_at (fp64 setup)
__global__ __launch_bounds__(256) void k_at(
    const float* __restrict__ Lam_ri, const float* __restrict__ p_ri,
    const float* __restrict__ q_ri,  const float* __restrict__ Vc_ri,
    const float* __restrict__ Ct_ri, const float* __restrict__ Bp,
    const float* __restrict__ log_step, float2* __restrict__ atroots) {
  __shared__ double2 lam[NST], ctB[NST], ctp[NST], qB[NST], qp[NST];
  __shared__ double stepd;
  int tx = threadIdx.x;
  if (tx < NST) {
    int n = tx;
    double lr = Lam_ri[2*n], li = Lam_ri[2*n+1];
    double pr = p_ri[2*n],  pi = p_ri[2*n+1];
    double qr = q_ri[2*n],  qi = q_ri[2*n+1];
    double cr = Ct_ri[2*n], ci = Ct_ri[2*n+1];
    double br = 0.0, bi = 0.0;
    for (int m = 0; m < NST; ++m) {
      double b = (double)Bp[m];
      br += (double)Vc_ri[2*(n*NST+m)]   * b;
      bi += (double)Vc_ri[2*(n*NST+m)+1] * b;
    }
    lam[n] = make_double2(lr, li);
    ctB[n] = make_double2(cr*br + ci*bi, cr*bi - ci*br);
    ctp[n] = make_double2(cr*pr + ci*pi, cr*pi - ci*pr);
    qB[n]  = make_double2(qr*br + qi*bi, qr*bi - qi*br);
    qp[n]  = make_double2(qr*pr + qi*pi, qr*pi - qi*pr);
  }
  if (tx == 0) stepd = exp((double)log_step[0]);
  __syncthreads();
  int l = blockIdx.x * 256 + tx;
  double ang = -2.0 * M_PI * (double)l / (double)SEQ_L;
  double sn, cs;
  sincos(ang, &sn, &cs);
  double2 onem = make_double2(1.0 - cs, -sn);
  double2 onep = make_double2(1.0 + cs,  sn);
  double den = onep.x*onep.x + onep.y*onep.y;
  double2 ip = make_double2(onep.x/den, -onep.y/den);
  double2 g  = dcmul(onem, ip);
  double tw = 2.0 / stepd;
  g.x *= tw; g.y *= tw;
  double2 cc = make_double2(2.0*ip.x, 2.0*ip.y);
  double2 k00 = make_double2(0,0), k01 = make_double2(0,0);
  double2 k10 = make_double2(0,0), k11 = make_double2(0,0);
  for (int n = 0; n < NST; ++n) {
    double2 L = lam[n];
    double2 d = make_double2(g.x - L.x, g.y - L.y);
    double dd = d.x*d.x + d.y*d.y;
    double2 inv = make_double2(d.x/dd, -d.y/dd);
    double2 v;
    v = ctB[n]; k00.x += v.x*inv.x - v.y*inv.y; k00.y += v.x*inv.y + v.y*inv.x;
    v = ctp[n]; k01.x += v.x*inv.x - v.y*inv.y; k01.y += v.x*inv.y + v.y*inv.x;
    v = qB[n];  k10.x += v.x*inv.x - v.y*inv.y; k10.y += v.x*inv.y + v.y*inv.x;
    v = qp[n];  k11.x += v.x*inv.x - v.y*inv.y; k11.y += v.x*inv.y + v.y*inv.x;
  }
  double2 k11p = make_double2(1.0 + k11.x, k11.y);
  double2 num  = dcmul(k01, k10);
  double dd2 = k11p.x*k11p.x + k11p.y*k11p.y;
  double2 t = make_double2((num.x*k11p.x + num.y*k11p.y)/dd2,
                           (num.y*k11p.x - num.x*k11p.y)/dd2);
  double2 inner = make_double2(k00.x - t.x, k00.y - t.y);
  double2 at = dcmul(cc, inner);
  atroots[l] = make_float2((float)at.x, (float)at.y);
}

// ---------------------------------------------------------------- k_kt (wave per t)
__global__ __launch_bounds__(512) void k_kt(const float2* __restrict__ atroots,
                                            float* __restrict__ Kt) {
  int gid  = blockIdx.x * 512 + threadIdx.x;
  int t    = gid >> 6;
  int lane = gid & 63;
  float acc = 0.f;
  for (int l = lane; l < SEQ_L; l += 64) {
    int ph = (l * t) & (SEQ_L - 1);
    float a = (float)ph * (TWO_PI / (float)SEQ_L);
    float sn, cs; __sincosf(a, &sn, &cs);
    float2 v = atroots[l];
    acc += v.x*cs - v.y*sn;
  }
  for (int off = 32; off > 0; off >>= 1) acc += __shfl_down(acc, off, 64);
  if (lane == 0) Kt[t] = acc * (1.0f / (float)SEQ_L);
}

// ---------------------------------------------------------------- k_kf
__global__ __launch_bounds__(1024) void k_kf(const float* __restrict__ Kt,
                                             cf* __restrict__ kf) {
  __shared__ cf lds[NFFT];
  int tid = threadIdx.x;
  cf x[8];
  #pragma unroll
  for (int m = 0; m < 4; ++m) x[m] = make_float2(Kt[tid + 1024*m], 0.f);
  #pragma unroll
  for (int m = 4; m < 8; ++m) x[m] = make_float2(0.f, 0.f);
  fwd_all<true>(x, lds, tid);
  const float s = 1.f / (float)NFFT;
  #pragma unroll
  for (int d = 0; d < 8; ++d)
    kf[tid*8 + d] = make_float2(x[d].x * s, x[d].y * s);
}

// ---------------------------------------------------------------- k_conv
__global__ __launch_bounds__(1024, 4) void k_conv(const float* __restrict__ u,
                                                  const cf* __restrict__ kf,
                                                  const float* __restrict__ Dp,
                                                  float* __restrict__ out) {
  __shared__ cf lds[NFFT];
  int tid = threadIdx.x;
  size_t row0 = (size_t)blockIdx.x * 2;
  const float* ru0 = u + row0 * SEQ_L;
  const float* ru1 = ru0 + SEQ_L;
  cf x[8];
  #pragma unroll
  for (int m = 0; m < 4; ++m) {
    int n = tid + 1024*m;
    x[m] = make_float2(ru0[n], ru1[n]);
  }
  #pragma unroll
  for (int m = 4; m < 8; ++m) x[m] = make_float2(0.f, 0.f);

  fwd_all<true>(x, lds, tid);

  // pointwise multiply with Kf (same permuted order, includes 1/8192)
  const float4* kf4 = (const float4*)kf + (size_t)tid * 4;
  #pragma unroll
  for (int k = 0; k < 4; ++k) {
    float4 kk = kf4[k];
    x[2*k]   = cmul(x[2*k],   make_float2(kk.x, kk.y));
    x[2*k+1] = cmul(x[2*k+1], make_float2(kk.z, kk.w));
  }

  inv_all(x, lds, tid);

  float Dv = Dp[0];
  float* o0 = out + row0 * SEQ_L;
  float* o1 = o0 + SEQ_L;
  #pragma unroll
  for (int m = 0; m < 4; ++m) {
    int n = tid + 1024*m;
    o0[n] = x[m].x + Dv * ru0[n];
    o1[n] = x[m].y + Dv * ru1[n];
  }
}

// ---------------------------------------------------------------- launch
extern "C" void kernel_launch(void* const* d_in, const int* in_sizes, int n_in,
                              void* d_out, int out_size, void* d_ws, size_t ws_size,
                              hipStream_t stream) {
  const float* u      = (const float*)d_in[0];
  const float* Lam_ri = (const float*)d_in[1];
  const float* p_ri   = (const float*)d_in[2];
  const float* q_ri   = (const float*)d_in[3];
  const float* Vc_ri  = (const float*)d_in[4];
  const float* Ct_ri  = (const float*)d_in[5];
  const float* Bp     = (const float*)d_in[6];
  const float* Dp     = (const float*)d_in[7];
  const float* ls     = (const float*)d_in[8];

  char* ws = (char*)d_ws;
  float2* atroots = (float2*)(ws);            // 32768 B
  float*  Kt      = (float*) (ws + 32768);    // 16384 B
  cf*     kf      = (cf*)    (ws + 49152);    // 65536 B (permuted order, /8192)

  k_at<<<dim3(SEQ_L/256), dim3(256), 0, stream>>>(Lam_ri, p_ri, q_ri, Vc_ri, Ct_ri, Bp, ls, atroots);
  k_kt<<<dim3(512), dim3(512), 0, stream>>>(atroots, Kt);
  k_kf<<<dim3(1), dim3(1024), 0, stream>>>(Kt, kf);
  k_conv<<<dim3(NROWS/2), dim3(1024), 0, stream>>>(u, kf, Dp, (float*)d_out);
}